// Round 3
// baseline (767.377 us; speedup 1.0000x reference)
//
#include <hip/hip_runtime.h>
#include <stdint.h>

typedef __attribute__((ext_vector_type(8))) short short8;
typedef __attribute__((ext_vector_type(4))) float f32x4;

#define B_ 2
#define H_ 16
#define S_ 2048
#define D_ 64
#define KB_ 64
#define NT_ (S_ / KB_)   // 32 k-tiles (== bits in one u32: tile index is the bit)

// fp32 pair -> packed bf16x2 (round-half-up; ties differ from RNE only)
__device__ __forceinline__ unsigned pk2(float x, float y) {
  const unsigned a = __builtin_bit_cast(unsigned, x) + 0x8000u;
  const unsigned b = __builtin_bit_cast(unsigned, y) + 0x8000u;
  return (a >> 16) | (b & 0xffff0000u);
}
__device__ __forceinline__ short b16(float x) {
  return (short)((__builtin_bit_cast(unsigned, x) + 0x8000u) >> 16);
}

// Raw barrier: cross-wave deps are LDS-only -> drain lgkm ONLY (T4: global
// prefetch loads / nontemporal A-stores stay in flight across barriers).
__device__ __forceinline__ void block_barrier() {
  __asm__ volatile("s_waitcnt lgkmcnt(0)\n\ts_barrier" ::: "memory");
}
__device__ __forceinline__ void lgkm0() {
  __asm__ volatile("s_waitcnt lgkmcnt(0)" ::: "memory");
}

__global__ __launch_bounds__(256, 4)
void attn_kernel(const float* __restrict__ Q, const float* __restrict__ K,
                 const float* __restrict__ V, const int* __restrict__ M,
                 float* __restrict__ O, float* __restrict__ A)
{
  // Bijective XCD-aware remap: XCD x gets heads {x, x+8, x+16, x+24}.
  const int bid = blockIdx.x + (blockIdx.y << 5);   // 0..1023
  const int qt  = (bid >> 3) & 31;                  // q-tile (64 rows)
  const int bh  = (bid & 7) | ((bid >> 8) << 3);    // b*H + h
  const int b   = bh >> 4;

  const int tid  = threadIdx.x;
  const int wave = tid >> 6;
  const int lane = tid & 63;
  const int l15  = lane & 15;
  const int quad = lane >> 4;

  const float* Qp = Q + (size_t)bh * S_ * D_;
  const float* Kp = K + (size_t)bh * S_ * D_;
  const float* Vp = V + (size_t)bh * S_ * D_;
  float* Op = O + (size_t)bh * S_ * D_;

  const int q0 = qt * 64 + wave * 16;   // this wave's 16 q-rows

  // Per-lane row pointers for mask / attn in C-layout (row = q0+4*quad+r).
  const int*  Mrow = M + (size_t)b  * S_ * S_ + (size_t)(q0 + 4 * quad) * S_ + l15;
  float*      Arow = A + (size_t)bh * S_ * S_ + (size_t)(q0 + 4 * quad) * S_ + l15;

  // LDS 27648 B. 144B row stride: b128 frag reads are conflict-free under
  // quarter-wave phasing (16 lanes x 16B = one 32-bank row; slot = (9*l15+c)
  // mod 8 covers each bank-slot exactly 2x). Staging writes are b64 2-way.
  __shared__ __attribute__((aligned(16))) short Ks[64][72];   // [kk][d]
  __shared__ __attribute__((aligned(16))) short Vt[64][72];   // [d][kk]
  __shared__ __attribute__((aligned(16))) short Pb[4][16][72];// per-wave P bf16

  // Q A-fragments (m=lane&15, k=quad*8+j+32h), pre-scaled by
  // 1/sqrt(D) * log2(e) so scores are in log2 domain (exp2 path).
  short8 aq[2];
  {
    const float c = 0.18033688011112042f;   // 0.125 * log2(e)
    const float* qr = Qp + (size_t)(q0 + l15) * D_ + quad * 8;
#pragma unroll
    for (int h = 0; h < 2; ++h) {
      const float4 x0 = *(const float4*)(qr + h * 32);
      const float4 x1 = *(const float4*)(qr + h * 32 + 4);
      union { unsigned u[4]; short8 s; } u;
      u.u[0] = pk2(x0.x * c, x0.y * c);
      u.u[1] = pk2(x0.z * c, x0.w * c);
      u.u[2] = pk2(x1.x * c, x1.y * c);
      u.u[3] = pk2(x1.z * c, x1.w * c);
      aq[h] = u.s;
    }
  }

  // K staging: row = tid>>2 (0..63), 4 cols at (tid&3)*4 + 16j  -> 4 b64 writes
  const int ksr = tid >> 2;
  const int ksc = (tid & 3) * 4;
  // V staging: 4x4 register transpose. Loads rows 4*(tid&15)+i, cols 4*(tid>>4);
  // writes d = 4*(tid>>4)+c as b64 of 4 consecutive kk  -> 2-way (free).
  const int vr4 = (tid & 15) * 4;
  const int vdc = (tid >> 4) * 4;

  float kbuf[16];
  float vbuf[4][4];   // [i][c] = V[kt+vr4+i][vdc+c]

  auto loadK = [&](int kt) {
#pragma unroll
    for (int j = 0; j < 4; ++j) {
      const float4 x = *(const float4*)(Kp + (size_t)(kt + ksr) * D_ + ksc + 16 * j);
      kbuf[4*j+0] = x.x; kbuf[4*j+1] = x.y; kbuf[4*j+2] = x.z; kbuf[4*j+3] = x.w;
    }
  };
  auto writeK = [&]() {
#pragma unroll
    for (int j = 0; j < 4; ++j)
      *(uint2*)&Ks[ksr][ksc + 16*j] =
        make_uint2(pk2(kbuf[4*j+0], kbuf[4*j+1]), pk2(kbuf[4*j+2], kbuf[4*j+3]));
  };
  auto loadV = [&](int kt) {
#pragma unroll
    for (int i = 0; i < 4; ++i) {
      const float4 x = *(const float4*)(Vp + (size_t)(kt + vr4 + i) * D_ + vdc);
      vbuf[i][0] = x.x; vbuf[i][1] = x.y; vbuf[i][2] = x.z; vbuf[i][3] = x.w;
    }
  };
  auto writeV = [&]() {
#pragma unroll
    for (int c = 0; c < 4; ++c)
      *(uint2*)&Vt[vdc + c][vr4] =
        make_uint2(pk2(vbuf[0][c], vbuf[1][c]), pk2(vbuf[2][c], vbuf[3][c]));
  };

  unsigned mreg[16];  // mask bits: mreg[nt*4+r] bit t  (static idx, dynamic shift)
#pragma unroll
  for (int i = 0; i < 16; ++i) mreg[i] = 0u;

  float lr[4];   // per-row -log2(denominator)

  // ---------------- pass 1: masked row sums (all in C-layout regs) ----------
  {
    float rowsum[4] = {0.f, 0.f, 0.f, 0.f};
    loadK(0);
    writeK();
    block_barrier();
    for (int t = 0; t < NT_; ++t) {
      const int kt = t * KB_;
      if (t + 1 < NT_) loadK(kt + KB_);          // prefetch (stays in flight)
      int mv[16];
#pragma unroll
      for (int nt = 0; nt < 4; ++nt)
#pragma unroll
        for (int r = 0; r < 4; ++r)              // C-layout mask: 4x64B dense/instr
          mv[nt*4+r] = Mrow[(size_t)r * S_ + kt + 16*nt];

      f32x4 acc[4] = {{0,0,0,0},{0,0,0,0},{0,0,0,0},{0,0,0,0}};
      __builtin_amdgcn_s_setprio(1);
#pragma unroll
      for (int nt = 0; nt < 4; ++nt)
#pragma unroll
        for (int h = 0; h < 2; ++h) {
          const short8 bk = *(const short8*)&Ks[nt*16 + l15][h*32 + quad*8];
          acc[nt] = __builtin_amdgcn_mfma_f32_16x16x32_bf16(aq[h], bk, acc[nt], 0, 0, 0);
        }
      __builtin_amdgcn_s_setprio(0);
#pragma unroll
      for (int nt = 0; nt < 4; ++nt)
#pragma unroll
        for (int r = 0; r < 4; ++r) {
          const unsigned p = (mv[nt*4+r] != 0) ? 1u : 0u;
          mreg[nt*4+r] |= p << t;
          rowsum[r] += p ? exp2f(acc[nt][r]) : 0.f;
        }
      block_barrier();                   // all waves done reading Ks[t]
      if (t + 1 < NT_) writeK();
      block_barrier();
    }
#pragma unroll
    for (int i = 0; i < 4; ++i) {
      float s = rowsum[i];
      s += __shfl_xor(s, 1);
      s += __shfl_xor(s, 2);
      s += __shfl_xor(s, 4);
      s += __shfl_xor(s, 8);
      lr[i] = (s > 0.f) ? -__log2f(s) : 0.f;
    }
  }

  // ---------------- pass 2: attn write + PV ----------------
  f32x4 oacc[4] = {{0,0,0,0},{0,0,0,0},{0,0,0,0},{0,0,0,0}};
  loadK(0);
  loadV(0);
  writeK();          // safe: pass-1 trailing barrier drained all Ks readers
  writeV();
  block_barrier();
  for (int t = 0; t < NT_; ++t) {
    const int kt = t * KB_;
    if (t + 1 < NT_) { loadK(kt + KB_); loadV(kt + KB_); }

    f32x4 acc[4] = {{0,0,0,0},{0,0,0,0},{0,0,0,0},{0,0,0,0}};
    __builtin_amdgcn_s_setprio(1);
#pragma unroll
    for (int nt = 0; nt < 4; ++nt)
#pragma unroll
      for (int h = 0; h < 2; ++h) {
        const short8 bk = *(const short8*)&Ks[nt*16 + l15][h*32 + quad*8];
        acc[nt] = __builtin_amdgcn_mfma_f32_16x16x32_bf16(aq[h], bk, acc[nt], 0, 0, 0);
      }
    __builtin_amdgcn_s_setprio(0);

    // p = exp2(s + lr) (masked -> 0), A-store + Pb write, all in C-layout
#pragma unroll
    for (int nt = 0; nt < 4; ++nt)
#pragma unroll
      for (int r = 0; r < 4; ++r) {
        const unsigned bit = (mreg[nt*4+r] >> t) & 1u;
        const float sarg = bit ? (acc[nt][r] + lr[r]) : -1.0e5f;
        const float p = exp2f(sarg);
        __builtin_nontemporal_store(p, Arow + (size_t)r * S_ + kt + 16*nt);
        Pb[wave][quad*4 + r][nt*16 + l15] = b16(p);
      }
    lgkm0();   // own-wave RAW: Pb writes land before A-frag read

    const short8 pa0 = *(const short8*)&Pb[wave][l15][quad*8];
    const short8 pa1 = *(const short8*)&Pb[wave][l15][32 + quad*8];
    __builtin_amdgcn_s_setprio(1);
#pragma unroll
    for (int nt = 0; nt < 4; ++nt) {
      const short8 bv0 = *(const short8*)&Vt[nt*16 + l15][quad*8];
      const short8 bv1 = *(const short8*)&Vt[nt*16 + l15][32 + quad*8];
      oacc[nt] = __builtin_amdgcn_mfma_f32_16x16x32_bf16(pa0, bv0, oacc[nt], 0, 0, 0);
      oacc[nt] = __builtin_amdgcn_mfma_f32_16x16x32_bf16(pa1, bv1, oacc[nt], 0, 0, 0);
    }
    __builtin_amdgcn_s_setprio(0);
    block_barrier();                       // all waves done reading Ks/Vt[t]
    if (t + 1 < NT_) { writeK(); writeV(); }
    block_barrier();
  }

  // epilogue: O tile (C/D layout), 16-lane coalesced
#pragma unroll
  for (int nt = 0; nt < 4; ++nt)
#pragma unroll
    for (int r = 0; r < 4; ++r)
      Op[(size_t)(q0 + quad*4 + r) * D_ + nt*16 + l15] = oacc[nt][r];
}

extern "C" void kernel_launch(void* const* d_in, const int* in_sizes, int n_in,
                              void* d_out, int out_size, void* d_ws, size_t ws_size,
                              hipStream_t stream) {
  const float* q = (const float*)d_in[0];
  const float* k = (const float*)d_in[1];
  const float* v = (const float*)d_in[2];
  const int*   m = (const int*)d_in[3];
  float* out  = (float*)d_out;
  float* attn = out + (size_t)B_ * H_ * S_ * D_;   // tuple order: (out, attn)

  dim3 grid(S_ / 64, B_ * H_);
  attn_kernel<<<grid, 256, 0, stream>>>(q, k, v, m, out, attn);
}